// Round 1
// baseline (158.792 us; speedup 1.0000x reference)
//
#include <hip/hip_runtime.h>

typedef __bf16 v8bf __attribute__((ext_vector_type(8)));
typedef __bf16 v4bf __attribute__((ext_vector_type(4)));
typedef float  v4f  __attribute__((ext_vector_type(4)));

#define NI   31        // number of per-dim nets (D-1)
#define DD   32        // input dim
#define NHID 128       // hidden width
#define BT   128       // batch tile per block
#define NBT  256       // 32768 / BT
#define WS   136       // padded LDS stride (feat dim) in elements
#define SMEM_BYTES (2*NHID*WS*2 + BT*DD*2 + (3*NHID + 2*NHID + 2)*4)  // 80392

// ---------------- prep: transpose + bf16-convert weights into ws ----------------
__global__ void maf_prep(const float* __restrict__ W1, const float* __restrict__ W2,
                         const float* __restrict__ W3,
                         __bf16* __restrict__ WT2, __bf16* __restrict__ WT3,
                         __bf16* __restrict__ WT1) {
    int b = blockIdx.x, t = threadIdx.x;
    if (b < 2 * NI) {                 // W2/W3: [kin][fo] -> [fo][kin]
        int i = b % NI;
        const float* src = (b < NI ? W2 : W3) + (size_t)i * NHID * NHID;
        __bf16* dst = (b < NI ? WT2 : WT3) + (size_t)i * NHID * NHID;
        for (int j = 0; j < 64; ++j) {
            int e = j * 256 + t;
            int fo = e >> 7, kin = e & 127;
            dst[e] = (__bf16)src[kin * NHID + fo];
        }
    } else {                          // W1: [d][fo] -> [fo][d]
        int i = b - 2 * NI;
        const float* src = W1 + (size_t)i * DD * NHID;
        __bf16* dst = WT1 + (size_t)i * NHID * DD;
        for (int j = 0; j < 16; ++j) {
            int e = j * 256 + t;
            int fo = e >> 5, d = e & 31;
            dst[e] = (__bf16)src[d * NHID + fo];
        }
    }
}

// ---------------- init: z[:,0], log_det = p0.s ----------------
__global__ void maf_init(const float* __restrict__ x, const float* __restrict__ p0,
                         float* __restrict__ zout, float* __restrict__ ldout) {
    int row = blockIdx.x * 256 + threadIdx.x;     // 0..32767
    float s = p0[0], tt = p0[1];
    ldout[row] = s;
    zout[(size_t)row * DD] = x[(size_t)row * DD] * expf(s) + tt;
}

// ---------------- main fused kernel ----------------
__global__ __launch_bounds__(256, 2) void maf_main(
    const float* __restrict__ x,
    const __bf16* __restrict__ WT1, const __bf16* __restrict__ WT2,
    const __bf16* __restrict__ WT3,
    const float* __restrict__ b1, const float* __restrict__ b2,
    const float* __restrict__ b3,
    const float* __restrict__ W4, const float* __restrict__ b4,
    float* __restrict__ zout, float* __restrict__ ldout) {

    extern __shared__ __align__(16) char smem[];
    __bf16* wbuf = (__bf16*)smem;            // [128][WS]  current layer W^T
    __bf16* hbuf = wbuf + NHID * WS;         // [128][WS]  h, batch-major
    __bf16* xb   = hbuf + NHID * WS;         // [128][32]  x tile, bf16
    float*  bsm  = (float*)(xb + BT * DD);   // b1|b2|b3  (3*128)
    float*  w4s  = bsm + 3 * NHID;           // [128][2]
    float*  b4s  = w4s + 2 * NHID;           // [2]

    const int t  = threadIdx.x;
    const int i  = blockIdx.x >> 8;          // net index 0..30
    const int bt = blockIdx.x & 255;         // batch tile
    const int l  = t & 63;
    const int w  = t >> 6;
    const int c  = l & 15;                   // MFMA row/col within 16-tile
    const int g  = l >> 4;                   // K-subgroup 0..3
    const int wr = w >> 1;                   // wave feat half
    const int wc = w & 1;                    // wave batch half

    // ---- stage x tile, W1^T, biases, W4 ----
    {
        const float4* xsrc = (const float4*)(x + (size_t)bt * BT * DD);
        #pragma unroll
        for (int j = 0; j < 4; ++j) {
            int chunk = j * 256 + t;                     // 1024 chunks of 4 floats
            float4 v = xsrc[chunk];
            int row = chunk >> 3, d0 = (chunk & 7) << 2;
            v4bf pk = {(__bf16)v.x, (__bf16)v.y, (__bf16)v.z, (__bf16)v.w};
            *(v4bf*)&xb[row * DD + d0] = pk;
        }
        const uint4* wsrc = (const uint4*)(WT1 + (size_t)i * NHID * DD);
        #pragma unroll
        for (int j = 0; j < 2; ++j) {
            int chunk = j * 256 + t;                     // 512 chunks of 8 bf16
            uint4 v = wsrc[chunk];
            int fo = chunk >> 2, ks = chunk & 3;
            *(uint4*)&wbuf[fo * WS + ks * 8] = v;
        }
        if (t < NHID) {
            bsm[t]            = b1[i * NHID + t];
            bsm[NHID + t]     = b2[i * NHID + t];
            bsm[2 * NHID + t] = b3[i * NHID + t];
            w4s[2 * t]     = W4[(size_t)i * 2 * NHID + 2 * t];
            w4s[2 * t + 1] = W4[(size_t)i * 2 * NHID + 2 * t + 1];
        }
        if (t == 0) { b4s[0] = b4[2 * i]; b4s[1] = b4[2 * i + 1]; }
    }
    __syncthreads();

    v4f acc[4][4];
    v8bf af[4], bfr[4];

    // ================= layer 1: T1 = W1^T (128x32) * x^T (32xBT) =================
    #pragma unroll
    for (int mt = 0; mt < 4; ++mt)
        af[mt] = *(const v8bf*)&wbuf[(wr * 64 + mt * 16 + c) * WS + g * 8];
    #pragma unroll
    for (int nt = 0; nt < 4; ++nt)
        bfr[nt] = *(const v8bf*)&xb[(wc * 64 + nt * 16 + c) * DD + g * 8];
    #pragma unroll
    for (int mt = 0; mt < 4; ++mt)
        #pragma unroll
        for (int nt = 0; nt < 4; ++nt)
            acc[mt][nt] = __builtin_amdgcn_mfma_f32_16x16x32_bf16(
                af[mt], bfr[nt], (v4f){0.f, 0.f, 0.f, 0.f}, 0, 0, 0);

    // write h1 (hbuf untouched so far -> no barrier needed before writes)
    #pragma unroll
    for (int mt = 0; mt < 4; ++mt)
        #pragma unroll
        for (int nt = 0; nt < 4; ++nt) {
            int batch = wc * 64 + nt * 16 + c;
            int fb = wr * 64 + mt * 16 + 4 * g;
            v4bf pk;
            #pragma unroll
            for (int r = 0; r < 4; ++r) {
                float v = acc[mt][nt][r] + bsm[fb + r];
                v = v >= 0.f ? v : 0.2f * v;
                pk[r] = (__bf16)v;
            }
            *(v4bf*)&hbuf[batch * WS + fb] = pk;
        }
    __syncthreads();   // wbuf reads + h1 writes complete

    // stage W2^T
    {
        const uint4* wsrc = (const uint4*)(WT2 + (size_t)i * NHID * NHID);
        #pragma unroll
        for (int j = 0; j < 8; ++j) {
            int chunk = j * 256 + t;                     // 2048 chunks
            uint4 v = wsrc[chunk];
            int fo = chunk >> 4, ks = chunk & 15;
            *(uint4*)&wbuf[fo * WS + ks * 8] = v;
        }
    }
    __syncthreads();

    // ================= layer 2 =================
    #pragma unroll
    for (int mt = 0; mt < 4; ++mt)
        #pragma unroll
        for (int nt = 0; nt < 4; ++nt)
            acc[mt][nt] = (v4f){0.f, 0.f, 0.f, 0.f};
    #pragma unroll
    for (int ks = 0; ks < 4; ++ks) {
        #pragma unroll
        for (int mt = 0; mt < 4; ++mt)
            af[mt] = *(const v8bf*)&wbuf[(wr * 64 + mt * 16 + c) * WS + ks * 32 + g * 8];
        #pragma unroll
        for (int nt = 0; nt < 4; ++nt)
            bfr[nt] = *(const v8bf*)&hbuf[(wc * 64 + nt * 16 + c) * WS + ks * 32 + g * 8];
        #pragma unroll
        for (int mt = 0; mt < 4; ++mt)
            #pragma unroll
            for (int nt = 0; nt < 4; ++nt)
                acc[mt][nt] = __builtin_amdgcn_mfma_f32_16x16x32_bf16(
                    af[mt], bfr[nt], acc[mt][nt], 0, 0, 0);
    }
    __syncthreads();   // everyone done reading hbuf/wbuf

    // write h2 + stage W3^T
    #pragma unroll
    for (int mt = 0; mt < 4; ++mt)
        #pragma unroll
        for (int nt = 0; nt < 4; ++nt) {
            int batch = wc * 64 + nt * 16 + c;
            int fb = wr * 64 + mt * 16 + 4 * g;
            v4bf pk;
            #pragma unroll
            for (int r = 0; r < 4; ++r) {
                float v = acc[mt][nt][r] + bsm[NHID + fb + r];
                v = v >= 0.f ? v : 0.2f * v;
                pk[r] = (__bf16)v;
            }
            *(v4bf*)&hbuf[batch * WS + fb] = pk;
        }
    {
        const uint4* wsrc = (const uint4*)(WT3 + (size_t)i * NHID * NHID);
        #pragma unroll
        for (int j = 0; j < 8; ++j) {
            int chunk = j * 256 + t;
            uint4 v = wsrc[chunk];
            int fo = chunk >> 4, ks = chunk & 15;
            *(uint4*)&wbuf[fo * WS + ks * 8] = v;
        }
    }
    __syncthreads();

    // ================= layer 3 =================
    #pragma unroll
    for (int mt = 0; mt < 4; ++mt)
        #pragma unroll
        for (int nt = 0; nt < 4; ++nt)
            acc[mt][nt] = (v4f){0.f, 0.f, 0.f, 0.f};
    #pragma unroll
    for (int ks = 0; ks < 4; ++ks) {
        #pragma unroll
        for (int mt = 0; mt < 4; ++mt)
            af[mt] = *(const v8bf*)&wbuf[(wr * 64 + mt * 16 + c) * WS + ks * 32 + g * 8];
        #pragma unroll
        for (int nt = 0; nt < 4; ++nt)
            bfr[nt] = *(const v8bf*)&hbuf[(wc * 64 + nt * 16 + c) * WS + ks * 32 + g * 8];
        #pragma unroll
        for (int mt = 0; mt < 4; ++mt)
            #pragma unroll
            for (int nt = 0; nt < 4; ++nt)
                acc[mt][nt] = __builtin_amdgcn_mfma_f32_16x16x32_bf16(
                    af[mt], bfr[nt], acc[mt][nt], 0, 0, 0);
    }
    __syncthreads();

    // write h3
    #pragma unroll
    for (int mt = 0; mt < 4; ++mt)
        #pragma unroll
        for (int nt = 0; nt < 4; ++nt) {
            int batch = wc * 64 + nt * 16 + c;
            int fb = wr * 64 + mt * 16 + 4 * g;
            v4bf pk;
            #pragma unroll
            for (int r = 0; r < 4; ++r) {
                float v = acc[mt][nt][r] + bsm[2 * NHID + fb + r];
                v = v >= 0.f ? v : 0.2f * v;
                pk[r] = (__bf16)v;
            }
            *(v4bf*)&hbuf[batch * WS + fb] = pk;
        }
    __syncthreads();

    // ================= layer 4 (VALU): st = h3 @ W4 + b4 =================
    {
        int batch = t >> 1, o = t & 1;     // 128 rows x {s,t}
        float d = b4s[o];
        #pragma unroll
        for (int kc = 0; kc < 16; ++kc) {
            v8bf hv = *(const v8bf*)&hbuf[batch * WS + kc * 8];
            #pragma unroll
            for (int j = 0; j < 8; ++j)
                d += (float)hv[j] * w4s[(kc * 8 + j) * 2 + o];
        }
        float other = __shfl_xor(d, 1, 64);
        if (o == 0) {
            int row = bt * BT + batch;
            float xv = x[(size_t)row * DD + i + 1];        // full f32 x for z
            zout[(size_t)row * DD + i + 1] = xv * expf(d) + other;
            atomicAdd(&ldout[row], d);
        }
    }
}

extern "C" void kernel_launch(void* const* d_in, const int* in_sizes, int n_in,
                              void* d_out, int out_size, void* d_ws, size_t ws_size,
                              hipStream_t stream) {
    (void)in_sizes; (void)n_in; (void)out_size; (void)ws_size;
    const float* x  = (const float*)d_in[0];
    const float* p0 = (const float*)d_in[1];
    const float* W1 = (const float*)d_in[2];
    const float* b1 = (const float*)d_in[3];
    const float* W2 = (const float*)d_in[4];
    const float* b2 = (const float*)d_in[5];
    const float* W3 = (const float*)d_in[6];
    const float* b3 = (const float*)d_in[7];
    const float* W4 = (const float*)d_in[8];
    const float* b4 = (const float*)d_in[9];

    float* zout  = (float*)d_out;
    float* ldout = zout + (size_t)32768 * DD;

    __bf16* WT2 = (__bf16*)d_ws;                    // [31][128][128]
    __bf16* WT3 = WT2 + (size_t)NI * NHID * NHID;   // [31][128][128]
    __bf16* WT1 = WT3 + (size_t)NI * NHID * NHID;   // [31][128][32]

    hipFuncSetAttribute((const void*)maf_main,
                        hipFuncAttributeMaxDynamicSharedMemorySize, SMEM_BYTES);

    maf_prep<<<3 * NI, 256, 0, stream>>>(W1, W2, W3, WT2, WT3, WT1);
    maf_init<<<32768 / 256, 256, 0, stream>>>(x, p0, zout, ldout);
    maf_main<<<NI * NBT, 256, SMEM_BYTES, stream>>>(x, WT1, WT2, WT3,
                                                    b1, b2, b3, W4, b4, zout, ldout);
}